// Round 2
// baseline (372.917 us; speedup 1.0000x reference)
//
#include <hip/hip_runtime.h>
#include <hip/hip_bf16.h>

#define NN 50000
#define NE 1600000
#define HD 128
#define NR 16
#define NCB 1563                 // coarse bins, 32 dsts each
#define S2B 512                  // sort blocks
#define EPB (NE / S2B)           // 3125 edges per sort block (exact)
#define SLOT 2048                // rec slots per bin
#define NB 512                   // fine sort buckets = 16 rels * 32 subs
#define PREPH_BLKS 6250
#define PREPW_BLKS 1024

typedef __bf16 bf16x8 __attribute__((ext_vector_type(8)));
typedef unsigned short u16x8 __attribute__((ext_vector_type(8)));
typedef float f32x4 __attribute__((ext_vector_type(4)));

__device__ __forceinline__ unsigned short f2bf(float f) {
    union { float f; unsigned int u; } v; v.f = f;
    unsigned int u = v.u;
    u += 0x7FFFu + ((u >> 16) & 1u);   // round-to-nearest-even
    return (unsigned short)(u >> 16);
}
__device__ __forceinline__ float bflo(unsigned int u) {
    union { unsigned int u; float f; } v; v.u = u << 16; return v.f;
}
__device__ __forceinline__ float bfhi(unsigned int u) {
    union { unsigned int u; float f; } v; v.u = u & 0xFFFF0000u; return v.f;
}

// ---------------- 1: prep_h + prep_w + coarse histogram -------------------
__global__ __launch_bounds__(256) void prep_all(const int* __restrict__ node_ids,
                                                const float* __restrict__ emb,
                                                unsigned short* __restrict__ h_bf,
                                                const float* __restrict__ W,
                                                unsigned short* __restrict__ Wt,
                                                const int* __restrict__ dst,
                                                int* __restrict__ cntM) {
    const int b = blockIdx.x;
    const int t = threadIdx.x;
    if (b < PREPH_BLKS) {
        int gid = b * 256 + t;
        int row = gid >> 5;
        int c = (gid & 31) << 2;
        int nid = node_ids[row];
        if (nid < 0) nid = 0; if (nid >= NN) nid = NN - 1;
        float4 v = *(const float4*)(emb + (size_t)nid * HD + c);
        ushort4 o;
        o.x = f2bf(v.x); o.y = f2bf(v.y); o.z = f2bf(v.z); o.w = f2bf(v.w);
        *(ushort4*)(h_bf + (size_t)row * HD + c) = o;
    } else if (b < PREPH_BLKS + PREPW_BLKS) {
        int gid = (b - PREPH_BLKS) * 256 + t;
        int r = gid >> 14;
        int idx = gid & 16383;
        int k = idx >> 7;
        int o = idx & 127;
        Wt[(size_t)r * 16384 + (size_t)o * 128 + k] = f2bf(W[gid]);
    } else {
        // coarse histogram (LDS only), block-major count matrix
        __shared__ int h[NCB];
        const int sb = b - PREPH_BLKS - PREPW_BLKS;    // 0..511
        for (int i = t; i < NCB; i += 256) h[i] = 0;
        __syncthreads();
        const int base = sb * EPB;
        for (int i = t; i < EPB; i += 256)
            atomicAdd(&h[((unsigned)dst[base + i]) >> 5], 1);
        __syncthreads();
        for (int i = t; i < NCB; i += 256) cntM[sb * NCB + i] = h[i];
    }
}

// ---------------- 2: per-bin scan of 512 block-counts ---------------------
__global__ __launch_bounds__(256) void scanBins(int* __restrict__ cntM,
                                                int* __restrict__ binN) {
    __shared__ int s[256];
    const int t = threadIdx.x;
    const int bin = blockIdx.x;
    int v0 = cntM[(2 * t) * NCB + bin];
    int v1 = cntM[(2 * t + 1) * NCB + bin];
    s[t] = v0 + v1;
    __syncthreads();
    for (int off = 1; off < 256; off <<= 1) {
        int x = (t >= off) ? s[t - off] : 0;
        __syncthreads();
        s[t] += x;
        __syncthreads();
    }
    int total = s[255];
    int e0 = s[t] - v0 - v1;
    int e1 = e0 + v0;
    cntM[(2 * t) * NCB + bin]     = bin * SLOT + (e0 < SLOT ? e0 : SLOT);
    cntM[(2 * t + 1) * NCB + bin] = bin * SLOT + (e1 < SLOT ? e1 : SLOT);
    if (t == 255) binN[bin] = (total < SLOT) ? total : SLOT;
}

// ---------------- 3: coarse scatter (standalone, LDS cursors) -------------
__global__ __launch_bounds__(256) void s2_scatter(const int* __restrict__ src,
                                                  const int* __restrict__ dst,
                                                  const int* __restrict__ rel,
                                                  const float* __restrict__ norm,
                                                  const int* __restrict__ cntM,
                                                  uint2* __restrict__ recs) {
    __shared__ int cur[NCB];
    const int t = threadIdx.x, sb = blockIdx.x;
    for (int i = t; i < NCB; i += 256) cur[i] = cntM[sb * NCB + i];
    __syncthreads();
    const int base = sb * EPB;
    for (int i = t; i < EPB; i += 256) {
        int e = base + i;
        int d = dst[e];
        int bin = ((unsigned)d) >> 5;
        int p = atomicAdd(&cur[bin], 1);
        int binEnd = (bin + 1) * SLOT;
        if (p < binEnd) {
            unsigned x = (unsigned)src[e] | ((unsigned)rel[e] << 16)
                       | ((unsigned)(d & 31) << 20);
            recs[p] = make_uint2(x, __float_as_uint(norm[e]));
        }
    }
}

// ---------------- 4: fused sort + per-(dst,rel) aggregate + MFMA ----------
// out[d] = sum_r W[r]^T m[d,r],  m[d,r] = sum_{e:dst=d,rel=r} norm_e h[src_e]
// Gathers hit h_bf (12.8MB, L2/L3-resident) instead of the 204.8MB h_rel.
// m double-buffered in LDS (bf16, stride-68 words: 2-way bank alias = free);
// one barrier per rel lets MFMA(r) overlap gathers of agg(r+1).
__global__ __launch_bounds__(256, 4) void seg_mm(const int* __restrict__ binN,
                                                 const uint2* __restrict__ recs,
                                                 const unsigned int* __restrict__ hb,
                                                 const unsigned short* __restrict__ Wt,
                                                 float* __restrict__ out) {
    __shared__ int srcS[SLOT];               // 8 KB  (sorted by rel*32+sub)
    __shared__ float normS[SLOT];            // 8 KB
    __shared__ int h[NB];                    // hist, then reused as cursors
    __shared__ int sbx[NB + 1];
    __shared__ int sc[256];
    __shared__ __align__(16) unsigned m32[2][32][68];   // 17.4 KB dbuf
    const int t = threadIdx.x;
    const int bin = blockIdx.x;
    const int n = binN[bin];
    const uint2* rg = recs + (size_t)bin * SLOT;

    for (int i = t; i < NB; i += 256) h[i] = 0;
    __syncthreads();
    for (int i = t; i < n; i += 256) {
        unsigned x = rg[i].x;
        atomicAdd(&h[((x >> 16) & 15) * 32 + ((x >> 20) & 31)], 1);
    }
    __syncthreads();
    // parallel scan of 512 buckets (2 per thread)
    int v0 = h[2 * t], v1 = h[2 * t + 1];
    sc[t] = v0 + v1;
    __syncthreads();
    for (int off = 1; off < 256; off <<= 1) {
        int x = (t >= off) ? sc[t - off] : 0;
        __syncthreads();
        sc[t] += x;
        __syncthreads();
    }
    int e0 = sc[t] - v0 - v1;
    sbx[2 * t] = e0;
    sbx[2 * t + 1] = e0 + v0;
    if (t == 255) sbx[NB] = sc[255];
    h[2 * t] = e0;                 // reuse h as scatter cursors
    h[2 * t + 1] = e0 + v0;
    __syncthreads();
    // sorted scatter into LDS (records re-read from global: L2-hot)
    for (int i = t; i < n; i += 256) {
        uint2 r = rg[i];
        int key = ((r.x >> 16) & 15) * 32 + ((r.x >> 20) & 31);
        int p = atomicAdd(&h[key], 1);
        srcS[p] = r.x & 0xFFFF;
        normS[p] = __uint_as_float(r.y);
    }
    __syncthreads();

    const int lane = t & 63;
    const int w = t >> 6;
    const int l15 = lane & 15, lhi = lane >> 4;
    const int colBase = w * 32;            // wave's 32 output cols

    f32x4 acc[2][2];
    #pragma unroll
    for (int i = 0; i < 2; ++i)
        #pragma unroll
        for (int j = 0; j < 2; ++j)
            acc[i][j] = (f32x4){0.f, 0.f, 0.f, 0.f};

    for (int r = 0; r < NR; ++r) {
        const int p = r & 1;
        // ---- aggregate m[d,r] for 8 sub-dsts, 8 gathers in flight ----
        int beg[8], end[8];
        float A0[8], A1[8];
        int mx = 0;
        #pragma unroll
        for (int k = 0; k < 8; ++k) {
            beg[k] = sbx[r * 32 + w * 8 + k];
            end[k] = sbx[r * 32 + w * 8 + k + 1];
            A0[k] = 0.f; A1[k] = 0.f;
            int len = end[k] - beg[k];
            mx = len > mx ? len : mx;
        }
        for (int rd = 0; rd < mx; ++rd) {
            unsigned u[8]; float nm[8];
            #pragma unroll
            for (int k = 0; k < 8; ++k) {
                if (beg[k] + rd < end[k]) {
                    int s = srcS[beg[k] + rd];
                    nm[k] = normS[beg[k] + rd];
                    u[k] = hb[((unsigned)s << 6) + lane];
                }
            }
            #pragma unroll
            for (int k = 0; k < 8; ++k) {
                if (beg[k] + rd < end[k]) {
                    A0[k] += bflo(u[k]) * nm[k];
                    A1[k] += bfhi(u[k]) * nm[k];
                }
            }
        }
        #pragma unroll
        for (int k = 0; k < 8; ++k)
            m32[p][w * 8 + k][lane] =
                ((unsigned)f2bf(A1[k]) << 16) | (unsigned)f2bf(A0[k]);
        __syncthreads();
        // ---- MFMA: acc += m[32x128] @ W_r[128x128] (wave's 32 cols) ----
        const unsigned short* wp = Wt + ((size_t)r << 14);
        #pragma unroll
        for (int kt = 0; kt < 4; ++kt) {
            const int ko = kt * 32 + lhi * 8;
            bf16x8 aF[2], bF[2];
            #pragma unroll
            for (int ms = 0; ms < 2; ++ms) {
                u16x8 raw = *(const u16x8*)((const unsigned short*)&m32[p][ms * 16 + l15][0] + ko);
                aF[ms] = __builtin_bit_cast(bf16x8, raw);
            }
            #pragma unroll
            for (int nt = 0; nt < 2; ++nt) {
                u16x8 raw = *(const u16x8*)(wp + (size_t)(colBase + nt * 16 + l15) * 128 + ko);
                bF[nt] = __builtin_bit_cast(bf16x8, raw);
            }
            #pragma unroll
            for (int ms = 0; ms < 2; ++ms)
                #pragma unroll
                for (int nt = 0; nt < 2; ++nt)
                    acc[ms][nt] = __builtin_amdgcn_mfma_f32_16x16x32_bf16(
                        aF[ms], bF[nt], acc[ms][nt], 0, 0, 0);
        }
        // no barrier here: next iter writes m32[p^1]; the barrier inside the
        // next iteration (with its implicit lgkmcnt(0)) orders mfma(r) reads
        // of m32[p] before agg(r+2) overwrites it.
    }

    // ---- epilogue: C frag row = lhi*4+reg, col = l15 ----
    const int dbase = bin * 32;
    #pragma unroll
    for (int ms = 0; ms < 2; ++ms) {
        #pragma unroll
        for (int reg = 0; reg < 4; ++reg) {
            int d = dbase + ms * 16 + lhi * 4 + reg;
            if (d < NN) {
                #pragma unroll
                for (int nt = 0; nt < 2; ++nt)
                    out[(size_t)d * 128 + colBase + nt * 16 + l15] = acc[ms][nt][reg];
            }
        }
    }
}

// ---------------- launch ---------------------------------------------------

extern "C" void kernel_launch(void* const* d_in, const int* in_sizes, int n_in,
                              void* d_out, int out_size, void* d_ws, size_t ws_size,
                              hipStream_t stream) {
    const int* node_ids = (const int*)d_in[0];
    const int* src      = (const int*)d_in[1];
    const int* dst      = (const int*)d_in[2];
    const int* rel      = (const int*)d_in[3];
    const float* norm   = (const float*)d_in[4];
    const float* emb    = (const float*)d_in[5];
    const float* W      = (const float*)d_in[6];
    float* out = (float*)d_out;

    char* ws = (char*)d_ws;
    unsigned short* h_bf = (unsigned short*)(ws);              // 12,800,000 B
    unsigned short* Wt   = (unsigned short*)(ws + 12800000);   //    524,288 B
    int* cntM            = (int*)(ws + 13324288);              //  3,201,024 B
    int* binN            = (int*)(ws + 16525312);              //      6,252 B
    uint2* recs          = (uint2*)(ws + 16531712);            // 25,608,192 B
    // total ~42.1 MB (h_rel eliminated)

    prep_all<<<PREPH_BLKS + PREPW_BLKS + S2B, 256, 0, stream>>>(
        node_ids, emb, h_bf, W, Wt, dst, cntM);
    scanBins<<<NCB, 256, 0, stream>>>(cntM, binN);
    s2_scatter<<<S2B, 256, 0, stream>>>(src, dst, rel, norm, cntM, recs);
    seg_mm<<<NCB, 256, 0, stream>>>(binN, recs,
                                    (const unsigned int*)h_bf, Wt, out);
}